// Round 14
// baseline (492.291 us; speedup 1.0000x reference)
//
#include <hip/hip_runtime.h>
#include <hip/hip_bf16.h>
#include <cstdint>

// ---------------- problem constants ----------------
#define KNB      17          // 1+K neighbors
#define CH       53          // rppe channels
#define MP       16          // points per locse block
#define BM       64          // points per conv block
#define NTHR     512         // 8 waves
#define NRT      17          // row tiles in locse = MP*KNB/16
#define SE_LD    72          // se LDS row stride (bf16)
#define CATW     1120        // cat global row width: [att 1088 | pc 2 | pad 30]
#define RES_LD   552         // res LDS row stride (bf16), 16B-aligned rows
#define CHPTS    8192        // pipeline chunk (cat/chunk = 17.5 MB)

// packed bf16 B-fragment segments in d_ws (ushort element offsets)
// fragment packing (A and B operands use the same k-major layout):
//   elem(ks, nt, lane l, jj)  <->  W[k = 32*ks + 8*(l>>4) + jj][col = 16*nt + (l&15)]
#define NE_CONV  (35*34*512)
#define NE_MLP   (2*2*512)
#define NE_ATT   (2*4*512)
#define NE_SKIP  (2*2*512)
#define WS_MLP   (NE_CONV)
#define WS_ATT   (WS_MLP + NE_MLP)
#define WS_SKIP  (WS_ATT + NE_ATT)
#define WS_TOTAL (WS_SKIP + NE_SKIP)

// mixed-kernel LDS union: conv = 8192 astage + 70656 res + 2176 bias = 81,024 B
//                         locse = 39168 se + 2176 pcl + 128 + 256   = 41,728 B
#define SMEM_BYTES 81024

typedef __bf16 bf16x8 __attribute__((ext_vector_type(8)));
typedef float  f32x4  __attribute__((ext_vector_type(4)));
typedef unsigned short u16x4 __attribute__((ext_vector_type(4)));
typedef unsigned short u16x8 __attribute__((ext_vector_type(8)));

__device__ __forceinline__ unsigned short f2b(float f) {
    union { __bf16 h; unsigned short u; } v; v.h = (__bf16)f; return v.u;  // HW RNE
}
__device__ __forceinline__ float b2f(unsigned short b) {
    union { unsigned u; float f; } v; v.u = ((unsigned)b) << 16;
    return v.f;
}
__device__ __forceinline__ void gload_lds16(const void* g, void* l) {
    __builtin_amdgcn_global_load_lds(
        (const __attribute__((address_space(1))) unsigned int*)g,
        (__attribute__((address_space(3))) unsigned int*)l, 16, 0, 0);
}

// ---------------- weight prep: f32 -> packed bf16 fragments ----------------
__global__ void seac_prep(const float* __restrict__ Wmlp, const float* __restrict__ Watt,
                          const float* __restrict__ Wconv, const float* __restrict__ Wskip,
                          unsigned short* __restrict__ ws)
{
    int i = blockIdx.x * 256 + threadIdx.x;
    if (i >= WS_TOTAL) return;
    float v;
    if (i < WS_MLP) {                       // conv: K=1090 (cat order [att|pc], pad 1120), N=544
        int idx = i;
        int jj = idx & 7, l = (idx >> 3) & 63, t = idx >> 9;
        int nt = t % 34, ks = t / 34;
        int k = 32*ks + 8*(l >> 4) + jj;    // storage k in cat order
        int o = 16*nt + (l & 15);
        int ok;
        if (k < 1088)       ok = k + 2;     // att block
        else if (k == 1088) ok = 0;         // pc x
        else if (k == 1089) ok = 1;         // pc y
        else                ok = -1;        // pad
        v = (ok >= 0) ? Wconv[ok*544 + o] : 0.f;
    } else if (i < WS_ATT) {                // mlp: K=53 (pad 64), N=32
        int idx = i - WS_MLP;
        int jj = idx & 7, l = (idx >> 3) & 63, t = idx >> 9;
        int nt = t & 1, ks = t >> 1;
        int k = 32*ks + 8*(l >> 4) + jj;
        int o = 16*nt + (l & 15);
        v = (k < CH) ? Wmlp[k*32 + o] : 0.f;
    } else if (i < WS_SKIP) {               // att: K=64, N=64
        int idx = i - WS_ATT;
        int jj = idx & 7, l = (idx >> 3) & 63, t = idx >> 9;
        int nt = t & 3, ks = t >> 2;
        int k = 32*ks + 8*(l >> 4) + jj;
        int o = 16*nt + (l & 15);
        v = Watt[k*64 + o];
    } else {                                // skip: K=64 ([feats|res] order), N=32
        int idx = i - WS_SKIP;
        int jj = idx & 7, l = (idx >> 3) & 63, t = idx >> 9;
        int nt = t & 1, ks = t >> 1;
        int k = 32*ks + 8*(l >> 4) + jj;
        int o = 16*nt + (l & 15);
        v = Wskip[k*32 + o];
    }
    ws[i] = f2b(v);
}

// ---------------- locse body (champion, verbatim; smem carved) ----------------
__device__ void locse_body(unsigned char* smem,
    const float* __restrict__ pc, const float* __restrict__ feats,
    const float* __restrict__ bmlp, const float* __restrict__ batt,
    const unsigned short* __restrict__ ws, unsigned short* __restrict__ catg,
    long pbase, long cat0)
{
    unsigned short* se_l = (unsigned short*)smem;                    // 272*SE_LD us
    float (*pcl)[KNB][2] = (float (*)[KNB][2])(smem + 39168);        // [MP][KNB][2]
    float* bmlp_l = (float*)(smem + 39168 + 2176);
    float* batt_l = bmlp_l + 32;

    const int tid  = threadIdx.x;
    const int w    = tid >> 6;
    const int l    = tid & 63;
    const int g    = l >> 4;
    const int c15  = l & 15;
    const bf16x8* wsB8 = (const bf16x8*)ws;
    const long cbase = pbase - cat0;                 // cat-buffer-relative point base

    // ---- phase 0 ----
    if (tid < MP*KNB) {
        int p = tid / KNB, i = tid - p*KNB;
        float x = pc[(pbase + p)*(KNB*2) + 2*i];
        float y = pc[(pbase + p)*(KNB*2) + 2*i + 1];
        pcl[p][i][0] = x; pcl[p][i][1] = y;
    }
    for (int q = tid; q < MP*544/4; q += NTHR) {
        float4 f = *(const float4*)&feats[pbase*544 + 4*q];
        int e0 = 4*q; int p = e0 / 544; int rem = e0 - 544*p;
        int j = rem >> 5, c = rem & 31;
        u16x4 u; u[0] = f2b(f.x); u[1] = f2b(f.y); u[2] = f2b(f.z); u[3] = f2b(f.w);
        *(u16x4*)&se_l[(p*KNB + j)*SE_LD + 32 + c] = u;
    }
    if (tid < 32)                     bmlp_l[tid]      = bmlp[tid];
    else if (tid >= 64 && tid < 128)  batt_l[tid-64]   = batt[tid-64];
    __syncthreads();

    // ---- phase 1 (swapped mlp) ----
    {
        bf16x8 Bm[2][2];
        #pragma unroll
        for (int ks = 0; ks < 2; ++ks)
            #pragma unroll
            for (int nt = 0; nt < 2; ++nt)
                Bm[ks][nt] = wsB8[(WS_MLP >> 3) + (ks*2 + nt)*64 + l];
        float bch[2][4];
        #pragma unroll
        for (int nt = 0; nt < 2; ++nt)
            #pragma unroll
            for (int r = 0; r < 4; ++r) bch[nt][r] = bmlp_l[16*nt + 4*g + r];

        for (int mt = w; mt < NRT; mt += 8) {
            int row = 16*mt + c15;
            int p = row / KNB, j = row - p*KNB;
            float pjx = pcl[p][j][0], pjy = pcl[p][j][1];
            float nj = sqrtf(pjx*pjx + pjy*pjy);
            f32x4 acc0 = {0.f,0.f,0.f,0.f}, acc1 = {0.f,0.f,0.f,0.f};
            #pragma unroll
            for (int ks = 0; ks < 2; ++ks) {
                union { unsigned short u[8]; bf16x8 v; } a;
                #pragma unroll
                for (int jj = 0; jj < 8; ++jj) {
                    int k = 32*ks + 8*g + jj;
                    float vv;
                    if (k == 0) vv = pjx;
                    else if (k == 1) vv = pjy;
                    else if (k < CH) {
                        int kk = k - 2, ii = kk/3, t3 = kk - 3*ii;
                        vv = (t3 == 0) ? (pcl[p][ii][0] - pjx)
                           : (t3 == 1) ? (pcl[p][ii][1] - pjy) : nj;
                    } else vv = 0.f;
                    a.u[jj] = f2b(vv);
                }
                acc0 = __builtin_amdgcn_mfma_f32_16x16x32_bf16(Bm[ks][0], a.v, acc0, 0, 0, 0);
                acc1 = __builtin_amdgcn_mfma_f32_16x16x32_bf16(Bm[ks][1], a.v, acc1, 0, 0, 0);
            }
            u16x4 o0, o1;
            #pragma unroll
            for (int r = 0; r < 4; ++r) {
                o0[r] = f2b(fmaxf(acc0[r] + bch[0][r], 0.f));
                o1[r] = f2b(fmaxf(acc1[r] + bch[1][r], 0.f));
            }
            *(u16x4*)&se_l[row*SE_LD + 4*g]      = o0;
            *(u16x4*)&se_l[row*SE_LD + 16 + 4*g] = o1;
        }
    }
    __syncthreads();

    // ---- phase 2 (swapped att + softmax, in place) ----
    {
        bf16x8 Ba[2][4];
        #pragma unroll
        for (int ks = 0; ks < 2; ++ks)
            #pragma unroll
            for (int nt = 0; nt < 4; ++nt)
                Ba[ks][nt] = wsB8[(WS_ATT >> 3) + (ks*4 + nt)*64 + l];
        float bch[16];
        #pragma unroll
        for (int nt = 0; nt < 4; ++nt)
            #pragma unroll
            for (int r = 0; r < 4; ++r) bch[4*nt+r] = batt_l[16*nt + 4*g + r];

        for (int mt = w; mt < NRT; mt += 8) {
            int row = 16*mt + c15;
            bf16x8 b0 = *(const bf16x8*)&se_l[row*SE_LD + 8*g];
            bf16x8 b1 = *(const bf16x8*)&se_l[row*SE_LD + 32 + 8*g];
            f32x4 acc[4];
            #pragma unroll
            for (int nt = 0; nt < 4; ++nt) {
                f32x4 z = {0.f,0.f,0.f,0.f};
                acc[nt] = __builtin_amdgcn_mfma_f32_16x16x32_bf16(Ba[0][nt], b0, z,       0, 0, 0);
                acc[nt] = __builtin_amdgcn_mfma_f32_16x16x32_bf16(Ba[1][nt], b1, acc[nt], 0, 0, 0);
            }
            float vv[16];
            #pragma unroll
            for (int nt = 0; nt < 4; ++nt)
                #pragma unroll
                for (int r = 0; r < 4; ++r) vv[4*nt+r] = acc[nt][r] + bch[4*nt+r];
            float m = vv[0];
            #pragma unroll
            for (int i = 1; i < 16; ++i) m = fmaxf(m, vv[i]);
            m = fmaxf(m, __shfl_xor(m, 16)); m = fmaxf(m, __shfl_xor(m, 32));
            float s = 0.f;
            #pragma unroll
            for (int i = 0; i < 16; ++i) { vv[i] = __expf(vv[i] - m); s += vv[i]; }
            s += __shfl_xor(s, 16); s += __shfl_xor(s, 32);
            float inv = 1.f / s;
            #pragma unroll
            for (int nt = 0; nt < 4; ++nt) {
                u16x4 sv = *(const u16x4*)&se_l[row*SE_LD + 16*nt + 4*g];
                u16x4 ov;
                #pragma unroll
                for (int r = 0; r < 4; ++r) ov[r] = f2b(vv[4*nt+r]*inv * b2f(sv[r]));
                *(u16x4*)&se_l[row*SE_LD + 16*nt + 4*g] = ov;
            }
        }
    }
    __syncthreads();

    // ---- phase 3: bulk coalesced copy se_l -> catg ----
    for (int c = tid; c < MP*140; c += NTHR) {
        int p = c / 140, rem = c - 140*p;
        int e = 8*rem;
        u16x8 v;
        if (e < 1088) {
            int row = p*KNB + (e >> 6), col = e & 63;
            v = *(const u16x8*)&se_l[row*SE_LD + col];
        } else {
            #pragma unroll
            for (int q = 0; q < 8; ++q) v[q] = 0;
            if (e == 1088) { v[0] = f2b(pcl[p][0][0]); v[1] = f2b(pcl[p][0][1]); }
        }
        *(u16x8*)&catg[(cbase + p)*CATW + e] = v;
    }
}

// ---------------- conv body (champion R3 structure, verbatim; smem carved) ----------------
__device__ void conv_body(unsigned char* smem,
    const unsigned short* __restrict__ catg, const float* __restrict__ feats,
    const float* __restrict__ bconv, const float* __restrict__ bskip,
    const unsigned short* __restrict__ ws, float* __restrict__ out,
    long pbase, long cat0)
{
    unsigned short (*astage)[BM][32] = (unsigned short (*)[BM][32])smem;  // [2][64][32]
    unsigned short* res_l = (unsigned short*)(smem + 8192);               // BM*RES_LD
    float* bconv_l = (float*)(smem + 8192 + 70656);

    const int tid  = threadIdx.x;
    const int w    = tid >> 6;
    const int l    = tid & 63;
    const int g    = l >> 4;
    const int c15  = l & 15;
    const bf16x8* wsB8 = (const bf16x8*)ws;
    const long cbase = pbase - cat0;                 // cat-buffer-relative point base

    for (int i = tid; i < 544; i += NTHR) bconv_l[i] = bconv[i];

    if (tid < 256) {
        const unsigned short* gsrc = &catg[(cbase + (tid >> 2))*CATW + 8*(tid & 3)];
        gload_lds16(gsrc, &astage[0][16*(tid >> 6)][0]);
    }
    asm volatile("s_waitcnt vmcnt(0)" ::: "memory");
    __syncthreads();

    f32x4 acc[4][5];
    #pragma unroll
    for (int mt = 0; mt < 4; ++mt)
        #pragma unroll
        for (int t = 0; t < 5; ++t) { f32x4 z = {0.f,0.f,0.f,0.f}; acc[mt][t] = z; }

    int cur = 0;
    for (int ks = 0; ks < 35; ++ks) {
        if (ks + 1 < 35 && tid < 256) {
            const unsigned short* gsrc = &catg[(cbase + (tid >> 2))*CATW + 32*(ks+1) + 8*(tid & 3)];
            gload_lds16(gsrc, &astage[cur ^ 1][16*(tid >> 6)][0]);
        }
        bf16x8 a[4];
        #pragma unroll
        for (int mt = 0; mt < 4; ++mt)
            a[mt] = *(const bf16x8*)&astage[cur][16*mt + c15][8*g];
        #pragma unroll
        for (int t = 0; t < 5; ++t) {
            int nt = w + 8*t;
            if (nt < 34) {
                bf16x8 b = wsB8[(ks*34 + nt)*64 + l];
                #pragma unroll
                for (int mt = 0; mt < 4; ++mt)
                    acc[mt][t] = __builtin_amdgcn_mfma_f32_16x16x32_bf16(a[mt], b, acc[mt][t], 0, 0, 0);
            }
        }
        asm volatile("s_waitcnt vmcnt(0)" ::: "memory");
        __syncthreads();
        cur ^= 1;
    }

    // conv epilogue: relu(acc+bias) -> res_l
    #pragma unroll
    for (int t = 0; t < 5; ++t) {
        int nt = w + 8*t;
        if (nt < 34) {
            float bc = bconv_l[16*nt + c15];
            #pragma unroll
            for (int mt = 0; mt < 4; ++mt)
                #pragma unroll
                for (int r = 0; r < 4; ++r)
                    res_l[(16*mt + 4*g + r)*RES_LD + 16*nt + c15] =
                        f2b(fmaxf(acc[mt][t][r] + bc, 0.f));
        }
    }
    __syncthreads();

    // skip: out = relu([feats|res] @ W_skip + b)
    {
        bf16x8 Bs[2][2];
        #pragma unroll
        for (int ks = 0; ks < 2; ++ks)
            #pragma unroll
            for (int nt = 0; nt < 2; ++nt)
                Bs[ks][nt] = wsB8[(WS_SKIP >> 3) + (ks*2 + nt)*64 + l];
        float bs0 = bskip[c15], bs1 = bskip[16 + c15];

        for (int tt = 0; tt < 9; ++tt) {
            int mt2 = w + 8*tt;
            if (mt2 < 68) {
                int rr = 16*mt2 + c15;
                int pp = rr / 17, jn = rr - 17*pp;
                float4 f0 = *(const float4*)&feats[(pbase*KNB + rr)*32 + 8*g];
                float4 f1 = *(const float4*)&feats[(pbase*KNB + rr)*32 + 8*g + 4];
                union { unsigned short u[8]; bf16x8 v; } af;
                af.u[0]=f2b(f0.x); af.u[1]=f2b(f0.y); af.u[2]=f2b(f0.z); af.u[3]=f2b(f0.w);
                af.u[4]=f2b(f1.x); af.u[5]=f2b(f1.y); af.u[6]=f2b(f1.z); af.u[7]=f2b(f1.w);
                bf16x8 ar = *(const bf16x8*)&res_l[pp*RES_LD + 32*jn + 8*g];
                f32x4 z = {0.f,0.f,0.f,0.f};
                f32x4 a0 = __builtin_amdgcn_mfma_f32_16x16x32_bf16(af.v, Bs[0][0], z, 0, 0, 0);
                a0       = __builtin_amdgcn_mfma_f32_16x16x32_bf16(ar,   Bs[1][0], a0, 0, 0, 0);
                f32x4 a1 = __builtin_amdgcn_mfma_f32_16x16x32_bf16(af.v, Bs[0][1], z, 0, 0, 0);
                a1       = __builtin_amdgcn_mfma_f32_16x16x32_bf16(ar,   Bs[1][1], a1, 0, 0, 0);
                #pragma unroll
                for (int r = 0; r < 4; ++r) {
                    long orow = pbase*KNB + 16*mt2 + 4*g + r;
                    out[orow*32 + c15]      = fmaxf(a0[r] + bs0, 0.f);
                    out[orow*32 + 16 + c15] = fmaxf(a1[r] + bs1, 0.f);
                }
            }
        }
    }
}

// ---------------- mixed kernel: conv blocks (chunk i-1) + locse blocks (chunk i) ----------------
__global__ __launch_bounds__(NTHR, 4) void seac_mixed(
    const float* __restrict__ pc, const float* __restrict__ feats,
    const float* __restrict__ bmlp, const float* __restrict__ batt,
    const float* __restrict__ bconv, const float* __restrict__ bskip,
    const unsigned short* __restrict__ ws, unsigned short* __restrict__ catg,
    float* __restrict__ out,
    int nconv, int conv_pt0, int locse_pt0, int cat0)
{
    __shared__ __attribute__((aligned(16))) unsigned char smem[SMEM_BYTES];
    if ((int)blockIdx.x < nconv) {
        conv_body(smem, catg, feats, bconv, bskip, ws, out,
                  (long)conv_pt0 + (long)blockIdx.x * BM, (long)cat0);
    } else {
        locse_body(smem, pc, feats, bmlp, batt, ws, catg,
                   (long)locse_pt0 + (long)((int)blockIdx.x - nconv) * MP, (long)cat0);
    }
}

extern "C" void kernel_launch(void* const* d_in, const int* in_sizes, int n_in,
                              void* d_out, int out_size, void* d_ws, size_t ws_size,
                              hipStream_t stream)
{
    const float* pc    = (const float*)d_in[0];
    const float* feats = (const float*)d_in[1];
    const float* Wmlp  = (const float*)d_in[2];
    const float* bmlp  = (const float*)d_in[3];
    const float* Watt  = (const float*)d_in[4];
    const float* batt  = (const float*)d_in[5];
    const float* Wconv = (const float*)d_in[6];
    const float* bconv = (const float*)d_in[7];
    const float* Wskip = (const float*)d_in[8];
    const float* bskip = (const float*)d_in[9];
    float* out = (float*)d_out;
    unsigned short* ws16 = (unsigned short*)d_ws;

    long npts = in_sizes[0] / (KNB*2);              // B*N = 65536

    size_t frag_bytes = (size_t)WS_TOTAL * 2;
    size_t cat_off    = (frag_bytes + 255) & ~(size_t)255;
    unsigned short* catg = (unsigned short*)((char*)d_ws + cat_off);
    size_t avail = (ws_size > cat_off) ? (ws_size - cat_off) : 0;
    long maxpts = (long)(avail / (CATW * 2));

    int prep_blocks = (WS_TOTAL + 255) / 256;
    hipLaunchKernelGGL(seac_prep, dim3(prep_blocks), dim3(256), 0, stream,
                       Wmlp, Watt, Wconv, Wskip, ws16);

    if (maxpts >= npts) {
        // pipelined mixed launches: L0; (C0+L1); ...; (C6+L7); C7
        long nch = (npts + CHPTS - 1) / CHPTS;
        for (long i = 0; i <= nch; ++i) {
            long lbase = i * CHPTS;
            long lcnt  = (i < nch) ? ((npts - lbase < CHPTS) ? (npts - lbase) : CHPTS) : 0;
            long cbase = (i - 1) * CHPTS;
            long ccnt  = (i >= 1) ? ((npts - cbase < CHPTS) ? (npts - cbase) : CHPTS) : 0;
            int nconv = (int)(ccnt / BM);
            int nloc  = (int)(lcnt / MP);
            if (nconv + nloc == 0) continue;
            hipLaunchKernelGGL(seac_mixed, dim3(nconv + nloc), dim3(NTHR), 0, stream,
                               pc, feats, bmlp, batt, bconv, bskip, ws16, catg, out,
                               nconv, (int)cbase, (int)lbase, 0);
        }
    } else {
        // fallback: serial chunked (R10 schedule), chunk-relative cat buffer
        long chunk = (maxpts / BM) * BM;
        if (chunk < BM) chunk = BM;
        for (long base = 0; base < npts; base += chunk) {
            long c = npts - base; if (c > chunk) c = chunk;
            hipLaunchKernelGGL(seac_mixed, dim3((int)(c / MP)), dim3(NTHR), 0, stream,
                               pc, feats, bmlp, batt, bconv, bskip, ws16, catg, out,
                               0, 0, (int)base, (int)base);
            hipLaunchKernelGGL(seac_mixed, dim3((int)(c / BM)), dim3(NTHR), 0, stream,
                               pc, feats, bmlp, batt, bconv, bskip, ws16, catg, out,
                               (int)(c / BM), (int)base, 0, (int)base);
        }
    }
}

// Round 15
// 336.730 us; speedup vs baseline: 1.4620x; 1.4620x over previous
//
#include <hip/hip_runtime.h>
#include <hip/hip_bf16.h>
#include <cstdint>

// ---------------- problem constants ----------------
#define KNB      17          // 1+K neighbors
#define CH       53          // rppe channels
#define MP       16          // points per block (kernel A)
#define BM       64          // points per block (kernel B)
#define NTHR     512         // 8 waves
#define NRT      17          // row tiles in A = MP*KNB/16
#define SE_LD    72          // se LDS row stride (bf16)
#define RES_LD   552         // res LDS row stride (bf16), 16B-aligned rows

// catK: K-major cat scratch. Plane ks (0..34) holds 32 cat elements per point:
//   catK[ ks*cstride*32 + p_rel*32 + 0..31 ]  <->  cat[p][32*ks .. 32*ks+31]
// (cat order [att 1088 | pc 2 | pad 30]; cstride = points in this chunk)
// locse wave writes 1 KB contiguous per (ks); conv wave reads 1 KB contiguous per
// (mt, ks); block per-ks footprint = one sequential 4 KB region (DRAM-friendly).

// packed bf16 B-fragment segments in d_ws (ushort element offsets)
// fragment packing (A and B operands use the same k-major layout):
//   elem(ks, nt, lane l, jj)  <->  W[k = 32*ks + 8*(l>>4) + jj][col = 16*nt + (l&15)]
#define NE_CONV  (35*34*512)
#define NE_MLP   (2*2*512)
#define NE_ATT   (2*4*512)
#define NE_SKIP  (2*2*512)
#define WS_MLP   (NE_CONV)
#define WS_ATT   (WS_MLP + NE_MLP)
#define WS_SKIP  (WS_ATT + NE_ATT)
#define WS_TOTAL (WS_SKIP + NE_SKIP)

typedef __bf16 bf16x8 __attribute__((ext_vector_type(8)));
typedef float  f32x4  __attribute__((ext_vector_type(4)));
typedef unsigned short u16x4 __attribute__((ext_vector_type(4)));
typedef unsigned short u16x8 __attribute__((ext_vector_type(8)));

__device__ __forceinline__ unsigned short f2b(float f) {
    union { __bf16 h; unsigned short u; } v; v.h = (__bf16)f; return v.u;  // HW RNE
}
__device__ __forceinline__ float b2f(unsigned short b) {
    union { unsigned u; float f; } v; v.u = ((unsigned)b) << 16;
    return v.f;
}

// ---------------- weight prep: f32 -> packed bf16 fragments ----------------
__global__ void seac_prep(const float* __restrict__ Wmlp, const float* __restrict__ Watt,
                          const float* __restrict__ Wconv, const float* __restrict__ Wskip,
                          unsigned short* __restrict__ ws)
{
    int i = blockIdx.x * 256 + threadIdx.x;
    if (i >= WS_TOTAL) return;
    float v;
    if (i < WS_MLP) {                       // conv: K=1090 (cat order [att|pc], pad 1120), N=544
        int idx = i;
        int jj = idx & 7, l = (idx >> 3) & 63, t = idx >> 9;
        int nt = t % 34, ks = t / 34;
        int k = 32*ks + 8*(l >> 4) + jj;    // storage k in cat order
        int o = 16*nt + (l & 15);
        int ok;
        if (k < 1088)       ok = k + 2;     // att block
        else if (k == 1088) ok = 0;         // pc x
        else if (k == 1089) ok = 1;         // pc y
        else                ok = -1;        // pad
        v = (ok >= 0) ? Wconv[ok*544 + o] : 0.f;
    } else if (i < WS_ATT) {                // mlp: K=53 (pad 64), N=32
        int idx = i - WS_MLP;
        int jj = idx & 7, l = (idx >> 3) & 63, t = idx >> 9;
        int nt = t & 1, ks = t >> 1;
        int k = 32*ks + 8*(l >> 4) + jj;
        int o = 16*nt + (l & 15);
        v = (k < CH) ? Wmlp[k*32 + o] : 0.f;
    } else if (i < WS_SKIP) {               // att: K=64, N=64
        int idx = i - WS_ATT;
        int jj = idx & 7, l = (idx >> 3) & 63, t = idx >> 9;
        int nt = t & 3, ks = t >> 2;
        int k = 32*ks + 8*(l >> 4) + jj;
        int o = 16*nt + (l & 15);
        v = Watt[k*64 + o];
    } else {                                // skip: K=64 ([feats|res] order), N=32
        int idx = i - WS_SKIP;
        int jj = idx & 7, l = (idx >> 3) & 63, t = idx >> 9;
        int nt = t & 1, ks = t >> 1;
        int k = 32*ks + 8*(l >> 4) + jj;
        int o = 16*nt + (l & 15);
        v = Wskip[k*32 + o];
    }
    ws[i] = f2b(v);
}

// ---------------- kernel A: LocSE mlp + attention -> catK (K-major) ----------------
// LDS ~41.7 KB -> 3 blocks/CU   (champion body; only phase-3 dst layout changed)
__global__ __launch_bounds__(NTHR, 6) void seac_locse(
    const float* __restrict__ pc, const float* __restrict__ feats,
    const float* __restrict__ bmlp, const float* __restrict__ batt,
    const unsigned short* __restrict__ ws, unsigned short* __restrict__ catK,
    int pt0, int crel0, int cstride)
{
    __shared__ unsigned short se_l[272 * SE_LD];    // 39,168 B  rows p*17+j, cols [r(32)|feats(32)] -> att
    __shared__ float pcl[MP][KNB][2];               //  2,176 B
    __shared__ float bmlp_l[32];
    __shared__ float batt_l[64];

    const int tid  = threadIdx.x;
    const int w    = tid >> 6;
    const int l    = tid & 63;
    const int g    = l >> 4;
    const int c15  = l & 15;
    const long pbase = (long)pt0 + (long)blockIdx.x * MP;
    const long crel  = (long)crel0 + (long)blockIdx.x * MP;
    const bf16x8* wsB8 = (const bf16x8*)ws;

    // ---- phase 0: pc cache, feats->se[:,32:64], biases ----
    if (tid < MP*KNB) {
        int p = tid / KNB, i = tid - p*KNB;
        float x = pc[(pbase + p)*(KNB*2) + 2*i];
        float y = pc[(pbase + p)*(KNB*2) + 2*i + 1];
        pcl[p][i][0] = x; pcl[p][i][1] = y;
    }
    for (int q = tid; q < MP*544/4; q += NTHR) {            // 2176 quads
        float4 f = *(const float4*)&feats[pbase*544 + 4*q];
        int e0 = 4*q; int p = e0 / 544; int rem = e0 - 544*p;
        int j = rem >> 5, c = rem & 31;
        u16x4 u; u[0] = f2b(f.x); u[1] = f2b(f.y); u[2] = f2b(f.z); u[3] = f2b(f.w);
        *(u16x4*)&se_l[(p*KNB + j)*SE_LD + 32 + c] = u;
    }
    if (tid < 32)                     bmlp_l[tid]      = bmlp[tid];
    else if (tid >= 64 && tid < 128)  batt_l[tid-64]   = batt[tid-64];
    __syncthreads();

    // ---- phase 1 (swapped): r = relu(rppe @ W_mlp + b) -> se[:,0:32] ----
    {
        bf16x8 Bm[2][2];
        #pragma unroll
        for (int ks = 0; ks < 2; ++ks)
            #pragma unroll
            for (int nt = 0; nt < 2; ++nt)
                Bm[ks][nt] = wsB8[(WS_MLP >> 3) + (ks*2 + nt)*64 + l];
        float bch[2][4];
        #pragma unroll
        for (int nt = 0; nt < 2; ++nt)
            #pragma unroll
            for (int r = 0; r < 4; ++r) bch[nt][r] = bmlp_l[16*nt + 4*g + r];

        for (int mt = w; mt < NRT; mt += 8) {
            int row = 16*mt + c15;
            int p = row / KNB, j = row - p*KNB;
            float pjx = pcl[p][j][0], pjy = pcl[p][j][1];
            float nj = sqrtf(pjx*pjx + pjy*pjy);
            f32x4 acc0 = {0.f,0.f,0.f,0.f}, acc1 = {0.f,0.f,0.f,0.f};
            #pragma unroll
            for (int ks = 0; ks < 2; ++ks) {
                union { unsigned short u[8]; bf16x8 v; } a;
                #pragma unroll
                for (int jj = 0; jj < 8; ++jj) {
                    int k = 32*ks + 8*g + jj;
                    float vv;
                    if (k == 0) vv = pjx;
                    else if (k == 1) vv = pjy;
                    else if (k < CH) {
                        int kk = k - 2, ii = kk/3, t3 = kk - 3*ii;
                        vv = (t3 == 0) ? (pcl[p][ii][0] - pjx)
                           : (t3 == 1) ? (pcl[p][ii][1] - pjy) : nj;
                    } else vv = 0.f;
                    a.u[jj] = f2b(vv);
                }
                acc0 = __builtin_amdgcn_mfma_f32_16x16x32_bf16(Bm[ks][0], a.v, acc0, 0, 0, 0);
                acc1 = __builtin_amdgcn_mfma_f32_16x16x32_bf16(Bm[ks][1], a.v, acc1, 0, 0, 0);
            }
            u16x4 o0, o1;
            #pragma unroll
            for (int r = 0; r < 4; ++r) {
                o0[r] = f2b(fmaxf(acc0[r] + bch[0][r], 0.f));
                o1[r] = f2b(fmaxf(acc1[r] + bch[1][r], 0.f));
            }
            *(u16x4*)&se_l[row*SE_LD + 4*g]      = o0;
            *(u16x4*)&se_l[row*SE_LD + 16 + 4*g] = o1;
        }
    }
    __syncthreads();

    // ---- phase 2 (swapped): att = softmax(se @ W_att + b) * se -> se_l in place ----
    {
        bf16x8 Ba[2][4];
        #pragma unroll
        for (int ks = 0; ks < 2; ++ks)
            #pragma unroll
            for (int nt = 0; nt < 4; ++nt)
                Ba[ks][nt] = wsB8[(WS_ATT >> 3) + (ks*4 + nt)*64 + l];
        float bch[16];
        #pragma unroll
        for (int nt = 0; nt < 4; ++nt)
            #pragma unroll
            for (int r = 0; r < 4; ++r) bch[4*nt+r] = batt_l[16*nt + 4*g + r];

        for (int mt = w; mt < NRT; mt += 8) {
            int row = 16*mt + c15;
            bf16x8 b0 = *(const bf16x8*)&se_l[row*SE_LD + 8*g];
            bf16x8 b1 = *(const bf16x8*)&se_l[row*SE_LD + 32 + 8*g];
            f32x4 acc[4];
            #pragma unroll
            for (int nt = 0; nt < 4; ++nt) {
                f32x4 z = {0.f,0.f,0.f,0.f};
                acc[nt] = __builtin_amdgcn_mfma_f32_16x16x32_bf16(Ba[0][nt], b0, z,       0, 0, 0);
                acc[nt] = __builtin_amdgcn_mfma_f32_16x16x32_bf16(Ba[1][nt], b1, acc[nt], 0, 0, 0);
            }
            float vv[16];
            #pragma unroll
            for (int nt = 0; nt < 4; ++nt)
                #pragma unroll
                for (int r = 0; r < 4; ++r) vv[4*nt+r] = acc[nt][r] + bch[4*nt+r];
            float m = vv[0];
            #pragma unroll
            for (int i = 1; i < 16; ++i) m = fmaxf(m, vv[i]);
            m = fmaxf(m, __shfl_xor(m, 16)); m = fmaxf(m, __shfl_xor(m, 32));
            float s = 0.f;
            #pragma unroll
            for (int i = 0; i < 16; ++i) { vv[i] = __expf(vv[i] - m); s += vv[i]; }
            s += __shfl_xor(s, 16); s += __shfl_xor(s, 32);
            float inv = 1.f / s;
            #pragma unroll
            for (int nt = 0; nt < 4; ++nt) {
                u16x4 sv = *(const u16x4*)&se_l[row*SE_LD + 16*nt + 4*g];
                u16x4 ov;
                #pragma unroll
                for (int r = 0; r < 4; ++r) ov[r] = f2b(vv[4*nt+r]*inv * b2f(sv[r]));
                *(u16x4*)&se_l[row*SE_LD + 16*nt + 4*g] = ov;   // in place
            }
        }
    }
    __syncthreads();

    // ---- phase 3: write catK (K-major; each wave = 1 KB contiguous per ks) ----
    // granule c: ks = c>>6, idx = c&63 -> p = idx>>2, g2 = idx&3; e = 32*ks + 8*g2
    {
        const long cs32 = (long)cstride * 32;
        for (int c = tid; c < 2240; c += NTHR) {
            int ks = c >> 6, idx = c & 63;
            int p = idx >> 2, g2 = idx & 3;
            int e = 32*ks + 8*g2;
            u16x8 v;
            if (e < 1088) {
                int row = p*KNB + (e >> 6), col = e & 63;
                v = *(const u16x8*)&se_l[row*SE_LD + col];
            } else {
                #pragma unroll
                for (int q = 0; q < 8; ++q) v[q] = 0;
                if (e == 1088) { v[0] = f2b(pcl[p][0][0]); v[1] = f2b(pcl[p][0][1]); }
            }
            *(u16x8*)&catK[(long)ks*cs32 + (crel + p)*32 + 8*g2] = v;
        }
    }
}

// ---------------- kernel B: conv GEMM (direct K-major A, lockstep waves) + skip ----------------
// LDS = 70,656 (res) + 2,176 = 72,832 B -> 2 blocks/CU (16 waves).
// K-loop: per-wave A-load = contiguous 1 KB from catK (16 pts x 64 B); 8x wave reuse
// served by L1 via raw s_barrier lockstep; NO LDS staging, NO vmcnt drains -> the
// B-weight stream is never forcibly drained (the champion's structural stall).
__global__ __launch_bounds__(NTHR, 4) void seac_conv(
    const unsigned short* __restrict__ catK, const float* __restrict__ feats,
    const float* __restrict__ bconv, const float* __restrict__ bskip,
    const unsigned short* __restrict__ ws, float* __restrict__ out,
    int pt0, int crel0, int cstride)
{
    __shared__ unsigned short res_l[BM * RES_LD];   // 70,656 B
    __shared__ float bconv_l[544];                  //  2,176 B

    const int tid  = threadIdx.x;
    const int w    = tid >> 6;
    const int l    = tid & 63;
    const int g    = l >> 4;
    const int c15  = l & 15;
    const long pbase = (long)pt0 + (long)blockIdx.x * BM;
    const long crel  = (long)crel0 + (long)blockIdx.x * BM;
    const bf16x8* wsB8 = (const bf16x8*)ws;

    for (int i = tid; i < 544; i += NTHR) bconv_l[i] = bconv[i];
    __syncthreads();

    const long cs32 = (long)cstride * 32;
    f32x4 acc[4][5];
    #pragma unroll
    for (int mt = 0; mt < 4; ++mt)
        #pragma unroll
        for (int t = 0; t < 5; ++t) { f32x4 z = {0.f,0.f,0.f,0.f}; acc[mt][t] = z; }

    for (int ks = 0; ks < 35; ++ks) {
        const unsigned short* pl = catK + (long)ks*cs32 + crel*32;
        bf16x8 a[4];
        #pragma unroll
        for (int mt = 0; mt < 4; ++mt)
            a[mt] = *(const bf16x8*)&pl[(16*mt + c15)*32 + 8*g];   // 1 KB/wave contiguous
        #pragma unroll
        for (int t = 0; t < 5; ++t) {
            int nt = w + 8*t;
            if (nt < 34) {
                bf16x8 b = wsB8[(ks*34 + nt)*64 + l];
                #pragma unroll
                for (int mt = 0; mt < 4; ++mt)
                    acc[mt][t] = __builtin_amdgcn_mfma_f32_16x16x32_bf16(a[mt], b, acc[mt][t], 0, 0, 0);
            }
        }
        __builtin_amdgcn_s_barrier();       // lockstep only (no drain): keep 8 waves
                                            // inside the same 4 KB A-window for L1 reuse
    }

    // conv epilogue: relu(acc+bias) -> res_l  (D: row=16mt+4g+r, col=16nt+c15)
    #pragma unroll
    for (int t = 0; t < 5; ++t) {
        int nt = w + 8*t;
        if (nt < 34) {
            float bc = bconv_l[16*nt + c15];
            #pragma unroll
            for (int mt = 0; mt < 4; ++mt)
                #pragma unroll
                for (int r = 0; r < 4; ++r)
                    res_l[(16*mt + 4*g + r)*RES_LD + 16*nt + c15] =
                        f2b(fmaxf(acc[mt][t][r] + bc, 0.f));
        }
    }
    __syncthreads();

    // skip: out = relu([feats|res] @ W_skip + b)  (rows rr = pp*17+j, 68 M-tiles)
    {
        bf16x8 Bs[2][2];
        #pragma unroll
        for (int ks = 0; ks < 2; ++ks)
            #pragma unroll
            for (int nt = 0; nt < 2; ++nt)
                Bs[ks][nt] = wsB8[(WS_SKIP >> 3) + (ks*2 + nt)*64 + l];
        float bs0 = bskip[c15], bs1 = bskip[16 + c15];

        for (int tt = 0; tt < 9; ++tt) {
            int mt2 = w + 8*tt;
            if (mt2 < 68) {
                int rr = 16*mt2 + c15;
                int pp = rr / 17, jn = rr - 17*pp;
                float4 f0 = *(const float4*)&feats[(pbase*KNB + rr)*32 + 8*g];
                float4 f1 = *(const float4*)&feats[(pbase*KNB + rr)*32 + 8*g + 4];
                union { unsigned short u[8]; bf16x8 v; } af;
                af.u[0]=f2b(f0.x); af.u[1]=f2b(f0.y); af.u[2]=f2b(f0.z); af.u[3]=f2b(f0.w);
                af.u[4]=f2b(f1.x); af.u[5]=f2b(f1.y); af.u[6]=f2b(f1.z); af.u[7]=f2b(f1.w);
                bf16x8 ar = *(const bf16x8*)&res_l[pp*RES_LD + 32*jn + 8*g];
                f32x4 z = {0.f,0.f,0.f,0.f};
                f32x4 a0 = __builtin_amdgcn_mfma_f32_16x16x32_bf16(af.v, Bs[0][0], z, 0, 0, 0);
                a0       = __builtin_amdgcn_mfma_f32_16x16x32_bf16(ar,   Bs[1][0], a0, 0, 0, 0);
                f32x4 a1 = __builtin_amdgcn_mfma_f32_16x16x32_bf16(af.v, Bs[0][1], z, 0, 0, 0);
                a1       = __builtin_amdgcn_mfma_f32_16x16x32_bf16(ar,   Bs[1][1], a1, 0, 0, 0);
                #pragma unroll
                for (int r = 0; r < 4; ++r) {
                    long orow = pbase*KNB + 16*mt2 + 4*g + r;
                    out[orow*32 + c15]      = fmaxf(a0[r] + bs0, 0.f);
                    out[orow*32 + 16 + c15] = fmaxf(a1[r] + bs1, 0.f);
                }
            }
        }
    }
}

extern "C" void kernel_launch(void* const* d_in, const int* in_sizes, int n_in,
                              void* d_out, int out_size, void* d_ws, size_t ws_size,
                              hipStream_t stream)
{
    const float* pc    = (const float*)d_in[0];
    const float* feats = (const float*)d_in[1];
    const float* Wmlp  = (const float*)d_in[2];
    const float* bmlp  = (const float*)d_in[3];
    const float* Watt  = (const float*)d_in[4];
    const float* batt  = (const float*)d_in[5];
    const float* Wconv = (const float*)d_in[6];
    const float* bconv = (const float*)d_in[7];
    const float* Wskip = (const float*)d_in[8];
    const float* bskip = (const float*)d_in[9];
    float* out = (float*)d_out;
    unsigned short* ws16 = (unsigned short*)d_ws;

    long npts = in_sizes[0] / (KNB*2);              // B*N = 65536

    // catK scratch after the weight fragments (2240 B per point total)
    size_t frag_bytes = (size_t)WS_TOTAL * 2;
    size_t cat_off    = (frag_bytes + 255) & ~(size_t)255;
    unsigned short* catK = (unsigned short*)((char*)d_ws + cat_off);
    size_t avail = (ws_size > cat_off) ? (ws_size - cat_off) : 0;
    long maxpts = (long)(avail / 2240);
    long chunk  = (maxpts / BM) * BM;
    if (chunk > npts) chunk = npts;
    if (chunk < BM)   chunk = BM;                   // assume ws_size >= ~2.5 MB

    int prep_blocks = (WS_TOTAL + 255) / 256;
    hipLaunchKernelGGL(seac_prep, dim3(prep_blocks), dim3(256), 0, stream,
                       Wmlp, Watt, Wconv, Wskip, ws16);

    for (long base = 0; base < npts; base += chunk) {
        long c = npts - base; if (c > chunk) c = chunk;
        hipLaunchKernelGGL(seac_locse, dim3((int)(c / MP)), dim3(NTHR), 0, stream,
                           pc, feats, bmlp, batt, ws16, catK,
                           (int)base, 0, (int)c);
        hipLaunchKernelGGL(seac_conv, dim3((int)(c / BM)), dim3(NTHR), 0, stream,
                           catK, feats, bconv, bskip, ws16, out,
                           (int)base, 0, (int)c);
    }
}

// Round 16
// 307.149 us; speedup vs baseline: 1.6028x; 1.0963x over previous
//
#include <hip/hip_runtime.h>
#include <hip/hip_bf16.h>
#include <cstdint>

// ---------------- problem constants ----------------
#define KNB      17          // 1+K neighbors
#define CH       53          // rppe channels
#define MP       16          // points per block (kernel A)
#define BM       64          // points per block (kernel B)
#define NTHR     512         // 8 waves
#define NRT      17          // row tiles in A = MP*KNB/16
#define SE_LD    72          // se LDS row stride (bf16)
#define CATW     1120        // cat global row width: [att 1088 | pc 2 | pad 30]
#define RES_LD   552         // res LDS row stride (bf16), 16B-aligned rows
#define CHUNK_PTS 32768      // L3 ping-pong: cat/chunk 73 MB + feats 71 MB fits 256 MB L3;
                             // conv grid stays 512 = 2 blocks/CU (R10's confound removed)

// packed bf16 B-fragment segments in d_ws (ushort element offsets)
// fragment packing (A and B operands use the same k-major layout):
//   elem(ks, nt, lane l, jj)  <->  W[k = 32*ks + 8*(l>>4) + jj][col = 16*nt + (l&15)]
#define NE_CONV  (35*34*512)
#define NE_MLP   (2*2*512)
#define NE_ATT   (2*4*512)
#define NE_SKIP  (2*2*512)
#define WS_MLP   (NE_CONV)
#define WS_ATT   (WS_MLP + NE_MLP)
#define WS_SKIP  (WS_ATT + NE_ATT)
#define WS_TOTAL (WS_SKIP + NE_SKIP)

typedef __bf16 bf16x8 __attribute__((ext_vector_type(8)));
typedef float  f32x4  __attribute__((ext_vector_type(4)));
typedef unsigned short u16x4 __attribute__((ext_vector_type(4)));
typedef unsigned short u16x8 __attribute__((ext_vector_type(8)));

__device__ __forceinline__ unsigned short f2b(float f) {
    union { __bf16 h; unsigned short u; } v; v.h = (__bf16)f; return v.u;  // HW RNE
}
__device__ __forceinline__ float b2f(unsigned short b) {
    union { unsigned u; float f; } v; v.u = ((unsigned)b) << 16;
    return v.f;
}
__device__ __forceinline__ void gload_lds16(const void* g, void* l) {
    __builtin_amdgcn_global_load_lds(
        (const __attribute__((address_space(1))) unsigned int*)g,
        (__attribute__((address_space(3))) unsigned int*)l, 16, 0, 0);
}

// ---------------- weight prep: f32 -> packed bf16 fragments ----------------
__global__ void seac_prep(const float* __restrict__ Wmlp, const float* __restrict__ Watt,
                          const float* __restrict__ Wconv, const float* __restrict__ Wskip,
                          unsigned short* __restrict__ ws)
{
    int i = blockIdx.x * 256 + threadIdx.x;
    if (i >= WS_TOTAL) return;
    float v;
    if (i < WS_MLP) {                       // conv: K=1090 (cat order [att|pc], pad 1120), N=544
        int idx = i;
        int jj = idx & 7, l = (idx >> 3) & 63, t = idx >> 9;
        int nt = t % 34, ks = t / 34;
        int k = 32*ks + 8*(l >> 4) + jj;    // storage k in cat order
        int o = 16*nt + (l & 15);
        int ok;
        if (k < 1088)       ok = k + 2;     // att block
        else if (k == 1088) ok = 0;         // pc x
        else if (k == 1089) ok = 1;         // pc y
        else                ok = -1;        // pad
        v = (ok >= 0) ? Wconv[ok*544 + o] : 0.f;
    } else if (i < WS_ATT) {                // mlp: K=53 (pad 64), N=32
        int idx = i - WS_MLP;
        int jj = idx & 7, l = (idx >> 3) & 63, t = idx >> 9;
        int nt = t & 1, ks = t >> 1;
        int k = 32*ks + 8*(l >> 4) + jj;
        int o = 16*nt + (l & 15);
        v = (k < CH) ? Wmlp[k*32 + o] : 0.f;
    } else if (i < WS_SKIP) {               // att: K=64, N=64
        int idx = i - WS_ATT;
        int jj = idx & 7, l = (idx >> 3) & 63, t = idx >> 9;
        int nt = t & 3, ks = t >> 2;
        int k = 32*ks + 8*(l >> 4) + jj;
        int o = 16*nt + (l & 15);
        v = Watt[k*64 + o];
    } else {                                // skip: K=64 ([feats|res] order), N=32
        int idx = i - WS_SKIP;
        int jj = idx & 7, l = (idx >> 3) & 63, t = idx >> 9;
        int nt = t & 1, ks = t >> 1;
        int k = 32*ks + 8*(l >> 4) + jj;
        int o = 16*nt + (l & 15);
        v = Wskip[k*32 + o];
    }
    ws[i] = f2b(v);
}

// ---------------- kernel A: LocSE mlp + attention -> cat (global, row-major) ----------------
// LDS ~41.7 KB -> 3 blocks/CU   (champion body, unchanged)
__global__ __launch_bounds__(NTHR, 6) void seac_locse(
    const float* __restrict__ pc, const float* __restrict__ feats,
    const float* __restrict__ bmlp, const float* __restrict__ batt,
    const unsigned short* __restrict__ ws, unsigned short* __restrict__ catg,
    int pt0)
{
    __shared__ unsigned short se_l[272 * SE_LD];    // 39,168 B  rows p*17+j, cols [r(32)|feats(32)] -> att
    __shared__ float pcl[MP][KNB][2];               //  2,176 B
    __shared__ float bmlp_l[32];
    __shared__ float batt_l[64];

    const int tid  = threadIdx.x;
    const int w    = tid >> 6;
    const int l    = tid & 63;
    const int g    = l >> 4;
    const int c15  = l & 15;
    const long pbase = (long)pt0 + (long)blockIdx.x * MP;
    const bf16x8* wsB8 = (const bf16x8*)ws;

    // ---- phase 0: pc cache, feats->se[:,32:64], biases ----
    if (tid < MP*KNB) {
        int p = tid / KNB, i = tid - p*KNB;
        float x = pc[(pbase + p)*(KNB*2) + 2*i];
        float y = pc[(pbase + p)*(KNB*2) + 2*i + 1];
        pcl[p][i][0] = x; pcl[p][i][1] = y;
    }
    for (int q = tid; q < MP*544/4; q += NTHR) {            // 2176 quads
        float4 f = *(const float4*)&feats[pbase*544 + 4*q];
        int e0 = 4*q; int p = e0 / 544; int rem = e0 - 544*p;
        int j = rem >> 5, c = rem & 31;
        u16x4 u; u[0] = f2b(f.x); u[1] = f2b(f.y); u[2] = f2b(f.z); u[3] = f2b(f.w);
        *(u16x4*)&se_l[(p*KNB + j)*SE_LD + 32 + c] = u;
    }
    if (tid < 32)                     bmlp_l[tid]      = bmlp[tid];
    else if (tid >= 64 && tid < 128)  batt_l[tid-64]   = batt[tid-64];
    __syncthreads();

    // ---- phase 1 (swapped): r = relu(rppe @ W_mlp + b) -> se[:,0:32] ----
    {
        bf16x8 Bm[2][2];
        #pragma unroll
        for (int ks = 0; ks < 2; ++ks)
            #pragma unroll
            for (int nt = 0; nt < 2; ++nt)
                Bm[ks][nt] = wsB8[(WS_MLP >> 3) + (ks*2 + nt)*64 + l];
        float bch[2][4];
        #pragma unroll
        for (int nt = 0; nt < 2; ++nt)
            #pragma unroll
            for (int r = 0; r < 4; ++r) bch[nt][r] = bmlp_l[16*nt + 4*g + r];

        for (int mt = w; mt < NRT; mt += 8) {
            int row = 16*mt + c15;
            int p = row / KNB, j = row - p*KNB;
            float pjx = pcl[p][j][0], pjy = pcl[p][j][1];
            float nj = sqrtf(pjx*pjx + pjy*pjy);
            f32x4 acc0 = {0.f,0.f,0.f,0.f}, acc1 = {0.f,0.f,0.f,0.f};
            #pragma unroll
            for (int ks = 0; ks < 2; ++ks) {
                union { unsigned short u[8]; bf16x8 v; } a;
                #pragma unroll
                for (int jj = 0; jj < 8; ++jj) {
                    int k = 32*ks + 8*g + jj;
                    float vv;
                    if (k == 0) vv = pjx;
                    else if (k == 1) vv = pjy;
                    else if (k < CH) {
                        int kk = k - 2, ii = kk/3, t3 = kk - 3*ii;
                        vv = (t3 == 0) ? (pcl[p][ii][0] - pjx)
                           : (t3 == 1) ? (pcl[p][ii][1] - pjy) : nj;
                    } else vv = 0.f;
                    a.u[jj] = f2b(vv);
                }
                acc0 = __builtin_amdgcn_mfma_f32_16x16x32_bf16(Bm[ks][0], a.v, acc0, 0, 0, 0);
                acc1 = __builtin_amdgcn_mfma_f32_16x16x32_bf16(Bm[ks][1], a.v, acc1, 0, 0, 0);
            }
            u16x4 o0, o1;
            #pragma unroll
            for (int r = 0; r < 4; ++r) {
                o0[r] = f2b(fmaxf(acc0[r] + bch[0][r], 0.f));
                o1[r] = f2b(fmaxf(acc1[r] + bch[1][r], 0.f));
            }
            *(u16x4*)&se_l[row*SE_LD + 4*g]      = o0;
            *(u16x4*)&se_l[row*SE_LD + 16 + 4*g] = o1;
        }
    }
    __syncthreads();

    // ---- phase 2 (swapped): att = softmax(se @ W_att + b) * se -> se_l in place ----
    {
        bf16x8 Ba[2][4];
        #pragma unroll
        for (int ks = 0; ks < 2; ++ks)
            #pragma unroll
            for (int nt = 0; nt < 4; ++nt)
                Ba[ks][nt] = wsB8[(WS_ATT >> 3) + (ks*4 + nt)*64 + l];
        float bch[16];
        #pragma unroll
        for (int nt = 0; nt < 4; ++nt)
            #pragma unroll
            for (int r = 0; r < 4; ++r) bch[4*nt+r] = batt_l[16*nt + 4*g + r];

        for (int mt = w; mt < NRT; mt += 8) {
            int row = 16*mt + c15;
            bf16x8 b0 = *(const bf16x8*)&se_l[row*SE_LD + 8*g];
            bf16x8 b1 = *(const bf16x8*)&se_l[row*SE_LD + 32 + 8*g];
            f32x4 acc[4];
            #pragma unroll
            for (int nt = 0; nt < 4; ++nt) {
                f32x4 z = {0.f,0.f,0.f,0.f};
                acc[nt] = __builtin_amdgcn_mfma_f32_16x16x32_bf16(Ba[0][nt], b0, z,       0, 0, 0);
                acc[nt] = __builtin_amdgcn_mfma_f32_16x16x32_bf16(Ba[1][nt], b1, acc[nt], 0, 0, 0);
            }
            float vv[16];
            #pragma unroll
            for (int nt = 0; nt < 4; ++nt)
                #pragma unroll
                for (int r = 0; r < 4; ++r) vv[4*nt+r] = acc[nt][r] + bch[4*nt+r];
            float m = vv[0];
            #pragma unroll
            for (int i = 1; i < 16; ++i) m = fmaxf(m, vv[i]);
            m = fmaxf(m, __shfl_xor(m, 16)); m = fmaxf(m, __shfl_xor(m, 32));
            float s = 0.f;
            #pragma unroll
            for (int i = 0; i < 16; ++i) { vv[i] = __expf(vv[i] - m); s += vv[i]; }
            s += __shfl_xor(s, 16); s += __shfl_xor(s, 32);
            float inv = 1.f / s;
            #pragma unroll
            for (int nt = 0; nt < 4; ++nt) {
                u16x4 sv = *(const u16x4*)&se_l[row*SE_LD + 16*nt + 4*g];
                u16x4 ov;
                #pragma unroll
                for (int r = 0; r < 4; ++r) ov[r] = f2b(vv[4*nt+r]*inv * b2f(sv[r]));
                *(u16x4*)&se_l[row*SE_LD + 16*nt + 4*g] = ov;   // in place
            }
        }
    }
    __syncthreads();

    // ---- phase 3: bulk coalesced copy se_l -> catg (16B/lane), incl pc+pad tail ----
    for (int c = tid; c < MP*140; c += NTHR) {              // 140 u16x8 chunks per point
        int p = c / 140, rem = c - 140*p;
        int e = 8*rem;
        u16x8 v;
        if (e < 1088) {
            int row = p*KNB + (e >> 6), col = e & 63;
            v = *(const u16x8*)&se_l[row*SE_LD + col];
        } else {
            #pragma unroll
            for (int q = 0; q < 8; ++q) v[q] = 0;
            if (e == 1088) { v[0] = f2b(pcl[p][0][0]); v[1] = f2b(pcl[p][0][1]); }
        }
        *(u16x8*)&catg[(pbase + p)*CATW + e] = v;
    }
}

// ---------------- kernel B: conv GEMM + fused skip (champion R3 structure) ----------------
// LDS = 8192 (astage dbuf 1ks) + 70656 (res full) + 2176 = 81,024 B -> 2 blocks/CU
__global__ __launch_bounds__(NTHR, 4) void seac_conv(
    const unsigned short* __restrict__ catg, const float* __restrict__ feats,
    const float* __restrict__ bconv, const float* __restrict__ bskip,
    const unsigned short* __restrict__ ws, float* __restrict__ out, int pt0)
{
    __shared__ unsigned short astage[2][BM][32];    //  8,192 B (A K-chunk dbuf)
    __shared__ unsigned short res_l[BM * RES_LD];   // 70,656 B
    __shared__ float bconv_l[544];                  //  2,176 B

    const int tid  = threadIdx.x;
    const int w    = tid >> 6;
    const int l    = tid & 63;
    const int g    = l >> 4;
    const int c15  = l & 15;
    const long pbase = (long)pt0 + (long)blockIdx.x * BM;
    const bf16x8* wsB8 = (const bf16x8*)ws;

    for (int i = tid; i < 544; i += NTHR) bconv_l[i] = bconv[i];

    // prologue: stage ks=0 (rows=tid>>2, 16B granule=tid&3; LDS dest wave-uniform+lane*16)
    if (tid < 256) {
        const unsigned short* gsrc = &catg[(pbase + (tid >> 2))*CATW + 8*(tid & 3)];
        gload_lds16(gsrc, &astage[0][16*(tid >> 6)][0]);
    }
    asm volatile("s_waitcnt vmcnt(0)" ::: "memory");
    __syncthreads();

    f32x4 acc[4][5];
    #pragma unroll
    for (int mt = 0; mt < 4; ++mt)
        #pragma unroll
        for (int t = 0; t < 5; ++t) { f32x4 z = {0.f,0.f,0.f,0.f}; acc[mt][t] = z; }

    int cur = 0;
    for (int ks = 0; ks < 35; ++ks) {
        if (ks + 1 < 35 && tid < 256) {
            const unsigned short* gsrc = &catg[(pbase + (tid >> 2))*CATW + 32*(ks+1) + 8*(tid & 3)];
            gload_lds16(gsrc, &astage[cur ^ 1][16*(tid >> 6)][0]);
        }
        bf16x8 a[4];
        #pragma unroll
        for (int mt = 0; mt < 4; ++mt)
            a[mt] = *(const bf16x8*)&astage[cur][16*mt + c15][8*g];
        #pragma unroll
        for (int t = 0; t < 5; ++t) {
            int nt = w + 8*t;
            if (nt < 34) {
                bf16x8 b = wsB8[(ks*34 + nt)*64 + l];
                #pragma unroll
                for (int mt = 0; mt < 4; ++mt)
                    acc[mt][t] = __builtin_amdgcn_mfma_f32_16x16x32_bf16(a[mt], b, acc[mt][t], 0, 0, 0);
            }
        }
        asm volatile("s_waitcnt vmcnt(0)" ::: "memory");
        __syncthreads();
        cur ^= 1;
    }

    // conv epilogue: relu(acc+bias) -> res_l  (D: row=16mt+4g+r, col=16nt+c15)
    #pragma unroll
    for (int t = 0; t < 5; ++t) {
        int nt = w + 8*t;
        if (nt < 34) {
            float bc = bconv_l[16*nt + c15];
            #pragma unroll
            for (int mt = 0; mt < 4; ++mt)
                #pragma unroll
                for (int r = 0; r < 4; ++r)
                    res_l[(16*mt + 4*g + r)*RES_LD + 16*nt + c15] =
                        f2b(fmaxf(acc[mt][t][r] + bc, 0.f));
        }
    }
    __syncthreads();

    // skip: out = relu([feats|res] @ W_skip + b)  (rows rr = pp*17+j, 68 M-tiles)
    {
        bf16x8 Bs[2][2];
        #pragma unroll
        for (int ks = 0; ks < 2; ++ks)
            #pragma unroll
            for (int nt = 0; nt < 2; ++nt)
                Bs[ks][nt] = wsB8[(WS_SKIP >> 3) + (ks*2 + nt)*64 + l];
        float bs0 = bskip[c15], bs1 = bskip[16 + c15];

        for (int tt = 0; tt < 9; ++tt) {
            int mt2 = w + 8*tt;
            if (mt2 < 68) {
                int rr = 16*mt2 + c15;
                int pp = rr / 17, jn = rr - 17*pp;
                float4 f0 = *(const float4*)&feats[(pbase*KNB + rr)*32 + 8*g];
                float4 f1 = *(const float4*)&feats[(pbase*KNB + rr)*32 + 8*g + 4];
                union { unsigned short u[8]; bf16x8 v; } af;
                af.u[0]=f2b(f0.x); af.u[1]=f2b(f0.y); af.u[2]=f2b(f0.z); af.u[3]=f2b(f0.w);
                af.u[4]=f2b(f1.x); af.u[5]=f2b(f1.y); af.u[6]=f2b(f1.z); af.u[7]=f2b(f1.w);
                bf16x8 ar = *(const bf16x8*)&res_l[pp*RES_LD + 32*jn + 8*g];
                f32x4 z = {0.f,0.f,0.f,0.f};
                f32x4 a0 = __builtin_amdgcn_mfma_f32_16x16x32_bf16(af.v, Bs[0][0], z, 0, 0, 0);
                a0       = __builtin_amdgcn_mfma_f32_16x16x32_bf16(ar,   Bs[1][0], a0, 0, 0, 0);
                f32x4 a1 = __builtin_amdgcn_mfma_f32_16x16x32_bf16(af.v, Bs[0][1], z, 0, 0, 0);
                a1       = __builtin_amdgcn_mfma_f32_16x16x32_bf16(ar,   Bs[1][1], a1, 0, 0, 0);
                #pragma unroll
                for (int r = 0; r < 4; ++r) {
                    long orow = pbase*KNB + 16*mt2 + 4*g + r;
                    out[orow*32 + c15]      = fmaxf(a0[r] + bs0, 0.f);
                    out[orow*32 + 16 + c15] = fmaxf(a1[r] + bs1, 0.f);
                }
            }
        }
    }
}

extern "C" void kernel_launch(void* const* d_in, const int* in_sizes, int n_in,
                              void* d_out, int out_size, void* d_ws, size_t ws_size,
                              hipStream_t stream)
{
    const float* pc    = (const float*)d_in[0];
    const float* feats = (const float*)d_in[1];
    const float* Wmlp  = (const float*)d_in[2];
    const float* bmlp  = (const float*)d_in[3];
    const float* Watt  = (const float*)d_in[4];
    const float* batt  = (const float*)d_in[5];
    const float* Wconv = (const float*)d_in[6];
    const float* bconv = (const float*)d_in[7];
    const float* Wskip = (const float*)d_in[8];
    const float* bskip = (const float*)d_in[9];
    float* out = (float*)d_out;
    unsigned short* ws16 = (unsigned short*)d_ws;

    int npts = in_sizes[0] / (KNB*2);               // B*N = 65536

    // cat scratch lives after the weight fragments in d_ws.
    // L3 ping-pong at CHUNK_PTS=32768: cat/chunk (73 MB) stays L3-resident between
    // locse and conv; BOTH grids remain at full occupancy (locse 2048, conv 512 =
    // 2 blocks/CU) -- removes R10's grid-collapse confound.
    size_t frag_bytes = (size_t)WS_TOTAL * 2;
    size_t cat_off    = (frag_bytes + 255) & ~(size_t)255;
    unsigned short* catg = (unsigned short*)((char*)d_ws + cat_off);
    size_t avail = (ws_size > cat_off) ? (ws_size - cat_off) : 0;
    long maxpts = (long)(avail / (CATW * 2));
    long chunk  = (maxpts / BM) * BM;
    if (chunk > CHUNK_PTS) chunk = CHUNK_PTS;
    if (chunk > npts) chunk = npts;
    if (chunk < BM)   chunk = BM;                   // assume ws_size >= ~2.5 MB

    int prep_blocks = (WS_TOTAL + 255) / 256;
    hipLaunchKernelGGL(seac_prep, dim3(prep_blocks), dim3(256), 0, stream,
                       Wmlp, Watt, Wconv, Wskip, ws16);

    for (long base = 0; base < npts; base += chunk) {
        long c = npts - base; if (c > chunk) c = chunk;
        hipLaunchKernelGGL(seac_locse, dim3((int)(c / MP)), dim3(NTHR), 0, stream,
                           pc, feats, bmlp, batt, ws16, catg, (int)base);
        hipLaunchKernelGGL(seac_conv, dim3((int)(c / BM)), dim3(NTHR), 0, stream,
                           catg, feats, bconv, bskip, ws16, out, (int)base);
    }
}